// Round 12
// baseline (131.410 us; speedup 1.0000x reference)
//
#include <hip/hip_runtime.h>

#define NN 8192
#define DD 128
#define CH 16           // column chunks
#define CPC (NN / CH)   // cols per chunk = 512
#define TILES (CPC / 64)
#define NPART 64        // partial-sum bins

typedef __bf16 bf16x8 __attribute__((ext_vector_type(8)));
typedef float f32x4 __attribute__((ext_vector_type(4)));

#define PACK_INIT __uint_as_float(0x7F7FFFFFu)

// Pack (score, idx): high 19 bits of fp32 score, idx in low 13 (rounds 5-11,
// absmax 0.0 throughout).
static __device__ __forceinline__ float packsi(float s, unsigned idx) {
  return __uint_as_float((__float_as_uint(s) & 0xFFFFE000u) | idx);
}

// Sorted-insert via med3: sk' = med3(v, s[k-1], sk), s0' = min — depth 1.
#define NET4(S0, S1, S2, S3, v)                                                \
  {                                                                            \
    float v_ = (v), o0 = S0, o1 = S1, o2 = S2;                                 \
    S0 = fminf(o0, v_);                                                        \
    S1 = __builtin_amdgcn_fmed3f(v_, o0, o1);                                  \
    S2 = __builtin_amdgcn_fmed3f(v_, o1, o2);                                  \
    S3 = __builtin_amdgcn_fmed3f(v_, o2, S3);                                  \
  }
#define NET5(S0, S1, S2, S3, S4, v)                                            \
  {                                                                            \
    float v_ = (v), o0 = S0, o1 = S1, o2 = S2, o3 = S3;                        \
    S0 = fminf(o0, v_);                                                        \
    S1 = __builtin_amdgcn_fmed3f(v_, o0, o1);                                  \
    S2 = __builtin_amdgcn_fmed3f(v_, o1, o2);                                  \
    S3 = __builtin_amdgcn_fmed3f(v_, o2, o3);                                  \
    S4 = __builtin_amdgcn_fmed3f(v_, o3, S4);                                  \
  }

static __device__ __forceinline__ unsigned short f2bf(float f) {
  unsigned u = __float_as_uint(f);
  u += 0x7FFFu + ((u >> 16) & 1u);   // round-to-nearest-even
  return (unsigned short)(u >> 16);
}

// Kernel 1: f32->bf16 convert, fp32 row sq-norms, zero bins + done counter.
__global__ __launch_bounds__(256) void prep_kernel(const float* __restrict__ x,
                                                   unsigned short* __restrict__ xb,
                                                   float* __restrict__ sq,
                                                   float* __restrict__ partial,
                                                   int* __restrict__ done) {
  const int wave = threadIdx.x >> 6, lane = threadIdx.x & 63;
  const int row = blockIdx.x * 4 + wave;
  const float2 v = ((const float2*)(x + (size_t)row * DD))[lane];
  float ss = v.x * v.x + v.y * v.y;
#pragma unroll
  for (int off = 32; off; off >>= 1) ss += __shfl_down(ss, off);
  if (lane == 0) sq[row] = ss;
  unsigned packed = (unsigned)f2bf(v.x) | ((unsigned)f2bf(v.y) << 16);
  ((unsigned*)(xb + (size_t)row * DD))[lane] = packed;
  if (blockIdx.x == 0) {
    if (threadIdx.x < NPART) partial[threadIdx.x] = 0.0f;
    if (threadIdx.x == 0) done[0] = 0;
  }
}

// Kernel 2: LDS-staged bf16-MFMA scores + med3 packed top-k.
// 64 rows/wave, 4 LDS buffers, 2 tiles per barrier phase (halves barrier
// count vs round 11). Block = 256 rows x 512 cols; grid (32,16) = 512
// blocks = 2/CU (LDS 65.5 KB x 2 = 131 KB <= 160). Off-diagonal blocks
// keep top-4 (self absent); diagonal blocks (bx>>1==by) keep top-5.
__global__ __launch_bounds__(256, 2) void dist_topk_kernel(
    const unsigned short* __restrict__ xb, const float* __restrict__ sq,
    float* __restrict__ pscore) {
  const int t = threadIdx.x;
  const int wave = t >> 6, lane = t & 63;
  const int lrow = lane & 15, lquad = lane >> 4;
  const int rowBase = blockIdx.x * 256;
  const int chunk = blockIdx.y;
  const int j0 = chunk * CPC;
  const bool hasDiag = ((blockIdx.x >> 1) == (int)blockIdx.y);

  __shared__ unsigned short colsB[4][64 * DD];   // 4 x 16 KB, XOR-swizzled
  __shared__ float sqs[4][64];

  // A fragments for 4 row-groups: lane holds X[row][k=lquad*8+j].
  const int r0 = rowBase + wave * 64 + lrow;     // group g row = r0 + g*16
  const unsigned short* ap0 = xb + (size_t)(r0)*DD + lquad * 8;
  const unsigned short* ap1 = xb + (size_t)(r0 + 16) * DD + lquad * 8;
  const unsigned short* ap2 = xb + (size_t)(r0 + 32) * DD + lquad * 8;
  const unsigned short* ap3 = xb + (size_t)(r0 + 48) * DD + lquad * 8;
  bf16x8 a00 = *(const bf16x8*)(ap0), a01 = *(const bf16x8*)(ap0 + 32),
         a02 = *(const bf16x8*)(ap0 + 64), a03 = *(const bf16x8*)(ap0 + 96);
  bf16x8 a10 = *(const bf16x8*)(ap1), a11 = *(const bf16x8*)(ap1 + 32),
         a12 = *(const bf16x8*)(ap1 + 64), a13 = *(const bf16x8*)(ap1 + 96);
  bf16x8 a20 = *(const bf16x8*)(ap2), a21 = *(const bf16x8*)(ap2 + 32),
         a22 = *(const bf16x8*)(ap2 + 64), a23 = *(const bf16x8*)(ap2 + 96);
  bf16x8 a30 = *(const bf16x8*)(ap3), a31 = *(const bf16x8*)(ap3 + 32),
         a32 = *(const bf16x8*)(ap3 + 64), a33 = *(const bf16x8*)(ap3 + 96);

  // Packed sorted lists, one per row-group, named scalars.
  float q00 = PACK_INIT, q01 = PACK_INIT, q02 = PACK_INIT, q03 = PACK_INIT,
        q04 = PACK_INIT;
  float q10 = PACK_INIT, q11 = PACK_INIT, q12 = PACK_INIT, q13 = PACK_INIT,
        q14 = PACK_INIT;
  float q20 = PACK_INIT, q21 = PACK_INIT, q22 = PACK_INIT, q23 = PACK_INIT,
        q24 = PACK_INIT;
  float q30 = PACK_INIT, q31 = PACK_INIT, q32 = PACK_INIT, q33 = PACK_INIT,
        q34 = PACK_INIT;

  // Staging closed-form swizzle (round-5 verified).
  const int sr = t >> 4, sch = t & 15;
  const int dst0 = (sr << 4) | (sch ^ (sr & 15));

  // Prefetch tiles 0 and 1.
  const float4* s0v = (const float4*)(xb + (size_t)j0 * DD);
  const float4* s1v = (const float4*)(xb + (size_t)(j0 + 64) * DD);
  float4 g0 = s0v[t], g1 = s0v[t + 256], g2 = s0v[t + 512], g3 = s0v[t + 768];
  float4 h0 = s1v[t], h1 = s1v[t + 256], h2 = s1v[t + 512], h3 = s1v[t + 768];
  float sqg = 0.0f, sqh = 0.0f;
  if (t < 64) { sqg = sq[j0 + t]; sqh = sq[j0 + 64 + t]; }

#define COMPUTE_TILE(CUR, JT, INSROW)                                          \
    _Pragma("unroll")                                                          \
    for (int ct = 0; ct < 4; ++ct) {                                           \
      const unsigned short* bb = &colsB[CUR][(ct * 16 + lrow) * DD];           \
      bf16x8 b0 = *(const bf16x8*)(bb + (((0 + lquad) ^ lrow) << 3));          \
      bf16x8 b1 = *(const bf16x8*)(bb + (((4 + lquad) ^ lrow) << 3));          \
      bf16x8 b2 = *(const bf16x8*)(bb + (((8 + lquad) ^ lrow) << 3));          \
      bf16x8 b3 = *(const bf16x8*)(bb + (((12 + lquad) ^ lrow) << 3));         \
      f32x4 ac0 = {0.f, 0.f, 0.f, 0.f}, ac1 = {0.f, 0.f, 0.f, 0.f};           \
      f32x4 ac2 = {0.f, 0.f, 0.f, 0.f}, ac3 = {0.f, 0.f, 0.f, 0.f};           \
      ac0 = __builtin_amdgcn_mfma_f32_16x16x32_bf16(b0, a00, ac0, 0, 0, 0);    \
      ac1 = __builtin_amdgcn_mfma_f32_16x16x32_bf16(b0, a10, ac1, 0, 0, 0);    \
      ac2 = __builtin_amdgcn_mfma_f32_16x16x32_bf16(b0, a20, ac2, 0, 0, 0);    \
      ac3 = __builtin_amdgcn_mfma_f32_16x16x32_bf16(b0, a30, ac3, 0, 0, 0);    \
      ac0 = __builtin_amdgcn_mfma_f32_16x16x32_bf16(b1, a01, ac0, 0, 0, 0);    \
      ac1 = __builtin_amdgcn_mfma_f32_16x16x32_bf16(b1, a11, ac1, 0, 0, 0);    \
      ac2 = __builtin_amdgcn_mfma_f32_16x16x32_bf16(b1, a21, ac2, 0, 0, 0);    \
      ac3 = __builtin_amdgcn_mfma_f32_16x16x32_bf16(b1, a31, ac3, 0, 0, 0);    \
      ac0 = __builtin_amdgcn_mfma_f32_16x16x32_bf16(b2, a02, ac0, 0, 0, 0);    \
      ac1 = __builtin_amdgcn_mfma_f32_16x16x32_bf16(b2, a12, ac1, 0, 0, 0);    \
      ac2 = __builtin_amdgcn_mfma_f32_16x16x32_bf16(b2, a22, ac2, 0, 0, 0);    \
      ac3 = __builtin_amdgcn_mfma_f32_16x16x32_bf16(b2, a32, ac3, 0, 0, 0);    \
      ac0 = __builtin_amdgcn_mfma_f32_16x16x32_bf16(b3, a03, ac0, 0, 0, 0);    \
      ac1 = __builtin_amdgcn_mfma_f32_16x16x32_bf16(b3, a13, ac1, 0, 0, 0);    \
      ac2 = __builtin_amdgcn_mfma_f32_16x16x32_bf16(b3, a23, ac2, 0, 0, 0);    \
      ac3 = __builtin_amdgcn_mfma_f32_16x16x32_bf16(b3, a33, ac3, 0, 0, 0);    \
      const f32x4 sq4 = *(const f32x4*)&sqs[CUR][ct * 16 + lquad * 4];         \
      const unsigned colb = (unsigned)((JT) + ct * 16 + lquad * 4);            \
      _Pragma("unroll")                                                        \
      for (int r = 0; r < 4; ++r) {                                            \
        INSROW(0, packsi(fmaf(-2.0f, ac0[r], sq4[r]), colb + r));              \
        INSROW(1, packsi(fmaf(-2.0f, ac1[r], sq4[r]), colb + r));              \
        INSROW(2, packsi(fmaf(-2.0f, ac2[r], sq4[r]), colb + r));              \
        INSROW(3, packsi(fmaf(-2.0f, ac3[r], sq4[r]), colb + r));              \
      }                                                                        \
    }

// 2 tiles per barrier phase; buffers (it&3, it&3|1) alternate {0,1}/{2,3}.
// Writes to pair P at phase k+2 follow barrier(k+1), which follows all
// reads of pair P at phase k -> single barrier per phase is race-free.
#define KBODY(INSROW)                                                          \
  for (int it = 0; it < TILES; it += 2) {                                      \
    const int jt = j0 + it * 64;                                               \
    const int c0 = it & 3, c1 = (it & 3) | 1;                                  \
    {                                                                          \
      float4* d0 = (float4*)colsB[c0];                                         \
      d0[dst0] = g0; d0[dst0 + 256] = g1;                                      \
      d0[dst0 + 512] = g2; d0[dst0 + 768] = g3;                                \
      float4* d1 = (float4*)colsB[c1];                                         \
      d1[dst0] = h0; d1[dst0 + 256] = h1;                                      \
      d1[dst0 + 512] = h2; d1[dst0 + 768] = h3;                                \
      if (t < 64) { sqs[c0][t] = sqg; sqs[c1][t] = sqh; }                      \
    }                                                                          \
    __syncthreads();                                                           \
    if (it + 2 < TILES) {                                                      \
      const float4* n0 = (const float4*)(xb + (size_t)(jt + 128) * DD);        \
      const float4* n1 = (const float4*)(xb + (size_t)(jt + 192) * DD);        \
      g0 = n0[t]; g1 = n0[t + 256]; g2 = n0[t + 512]; g3 = n0[t + 768];        \
      h0 = n1[t]; h1 = n1[t + 256]; h2 = n1[t + 512]; h3 = n1[t + 768];        \
      if (t < 64) { sqg = sq[jt + 128 + t]; sqh = sq[jt + 192 + t]; }          \
    }                                                                          \
    COMPUTE_TILE(c0, jt, INSROW)                                               \
    COMPUTE_TILE(c1, jt + 64, INSROW)                                          \
  }

#define INS4(G, V) NET4(q##G##0, q##G##1, q##G##2, q##G##3, (V))
#define INS5(G, V) NET5(q##G##0, q##G##1, q##G##2, q##G##3, q##G##4, (V))

  if (hasDiag) {
    KBODY(INS5)
  } else {
    KBODY(INS4)
  }
#undef KBODY
#undef COMPUTE_TILE

  // Merge across lquads (lanes sharing lrow hold the same 4 rows).
#define MERGE4(G, M)                                                           \
  {                                                                            \
    float o0 = __shfl_xor(q##G##0, M), o1 = __shfl_xor(q##G##1, M),            \
          o2 = __shfl_xor(q##G##2, M), o3 = __shfl_xor(q##G##3, M);            \
    NET4(q##G##0, q##G##1, q##G##2, q##G##3, o0);                              \
    NET4(q##G##0, q##G##1, q##G##2, q##G##3, o1);                              \
    NET4(q##G##0, q##G##1, q##G##2, q##G##3, o2);                              \
    NET4(q##G##0, q##G##1, q##G##2, q##G##3, o3);                              \
  }
#define MERGE5(G, M)                                                           \
  {                                                                            \
    float o0 = __shfl_xor(q##G##0, M), o1 = __shfl_xor(q##G##1, M),            \
          o2 = __shfl_xor(q##G##2, M), o3 = __shfl_xor(q##G##3, M),            \
          o4 = __shfl_xor(q##G##4, M);                                         \
    NET5(q##G##0, q##G##1, q##G##2, q##G##3, q##G##4, o0);                     \
    NET5(q##G##0, q##G##1, q##G##2, q##G##3, q##G##4, o1);                     \
    NET5(q##G##0, q##G##1, q##G##2, q##G##3, q##G##4, o2);                     \
    NET5(q##G##0, q##G##1, q##G##2, q##G##3, q##G##4, o3);                     \
    NET5(q##G##0, q##G##1, q##G##2, q##G##3, q##G##4, o4);                     \
  }
  if (hasDiag) {
    MERGE5(0, 16) MERGE5(1, 16) MERGE5(2, 16) MERGE5(3, 16)
    MERGE5(0, 32) MERGE5(1, 32) MERGE5(2, 32) MERGE5(3, 32)
  } else {
    MERGE4(0, 16) MERGE4(1, 16) MERGE4(2, 16) MERGE4(3, 16)
    MERGE4(0, 32) MERGE4(1, 32) MERGE4(2, 32) MERGE4(3, 32)
  }

  if (lquad == 0) {
    // pscore layout: [row][CH*5] -> coalesced per-row read in final_kernel.
    float* b0p = pscore + (size_t)(r0)*80 + chunk * 5;
    b0p[0] = q00; b0p[1] = q01; b0p[2] = q02; b0p[3] = q03; b0p[4] = q04;
    float* b1p = pscore + (size_t)(r0 + 16) * 80 + chunk * 5;
    b1p[0] = q10; b1p[1] = q11; b1p[2] = q12; b1p[3] = q13; b1p[4] = q14;
    float* b2p = pscore + (size_t)(r0 + 32) * 80 + chunk * 5;
    b2p[0] = q20; b2p[1] = q21; b2p[2] = q22; b2p[3] = q23; b2p[4] = q24;
    float* b3p = pscore + (size_t)(r0 + 48) * 80 + chunk * 5;
    b3p[0] = q30; b3p[1] = q31; b3p[2] = q32; b3p[3] = q33; b3p[4] = q34;
  }
}

// Kernel 3: chunk merge -> neg idx -> exact fp32 hinge -> 64 atomic bins;
// LAST block (done-counter) folds the bins into the mean (saves the
// reduce dispatch). Bin adds are device-scope atomics; __threadfence
// orders each block's bin-add before its done-increment; the last block
// re-reads bins with atomicAdd(+0.0f) (coherent read path).
__global__ __launch_bounds__(256) void final_kernel(const float* __restrict__ x,
                                                    const float* __restrict__ pos,
                                                    const float* __restrict__ pscore,
                                                    float* __restrict__ partial,
                                                    int* __restrict__ done,
                                                    float* __restrict__ out) {
  const int wave = threadIdx.x >> 6, lane = threadIdx.x & 63;
  const int row = blockIdx.x * 4 + wave;

  float q0 = PACK_INIT, q1 = PACK_INIT, q2 = PACK_INIT, q3 = PACK_INIT,
        q4 = PACK_INIT;
  if (lane < CH) {
    const float* b = pscore + (size_t)row * 80 + lane * 5;   // contiguous row
    q0 = b[0]; q1 = b[1]; q2 = b[2]; q3 = b[3]; q4 = b[4];
  }
#pragma unroll
  for (int m = 1; m < CH; m <<= 1) {
    float o0 = __shfl_xor(q0, m), o1 = __shfl_xor(q1, m), o2 = __shfl_xor(q2, m),
          o3 = __shfl_xor(q3, m), o4 = __shfl_xor(q4, m);
    NET5(q0, q1, q2, q3, q4, o0);
    NET5(q0, q1, q2, q3, q4, o1);
    NET5(q0, q1, q2, q3, q4, o2);
    NET5(q0, q1, q2, q3, q4, o3);
    NET5(q0, q1, q2, q3, q4, o4);
  }
  const int nidx = (int)(__float_as_uint(__shfl(q4, 0)) & 0x1FFFu);

  const float2 xv  = ((const float2*)(x   + (size_t)row  * DD))[lane];
  const float2 pv  = ((const float2*)(pos + (size_t)row  * DD))[lane];
  const float2 nvv = ((const float2*)(x   + (size_t)nidx * DD))[lane];
  float a0 = xv.x - pv.x + 1e-6f, a1 = xv.y - pv.y + 1e-6f;
  float b0 = xv.x - nvv.x + 1e-6f, b1 = xv.y - nvv.y + 1e-6f;
  float dap = a0 * a0 + a1 * a1;
  float dan = b0 * b0 + b1 * b1;
#pragma unroll
  for (int off = 32; off; off >>= 1) {
    dap += __shfl_down(dap, off);
    dan += __shfl_down(dan, off);
  }
  __shared__ float hs[4];
  __shared__ int amlast;
  if (lane == 0) hs[wave] = fmaxf(sqrtf(dap) - sqrtf(dan) + 0.3f, 0.0f);
  __syncthreads();
  if (threadIdx.x == 0) {
    float s = hs[0] + hs[1] + hs[2] + hs[3];
    atomicAdd(&partial[blockIdx.x & (NPART - 1)], s);
    __threadfence();
    int v = atomicAdd(done, 1);
    amlast = (v == (int)gridDim.x - 1);
  }
  __syncthreads();
  if (amlast && threadIdx.x < NPART) {
    float v = atomicAdd(&partial[threadIdx.x], 0.0f);   // coherent read of bin
#pragma unroll
    for (int off = 32; off; off >>= 1) v += __shfl_down(v, off);
    if (threadIdx.x == 0) out[0] = v * (1.0f / 8192.0f);
  }
}

extern "C" void kernel_launch(void* const* d_in, const int* in_sizes, int n_in,
                              void* d_out, int out_size, void* d_ws, size_t ws_size,
                              hipStream_t stream) {
  const float* x   = (const float*)d_in[0];
  const float* pos = (const float*)d_in[1];
  float* out = (float*)d_out;

  char* w = (char*)d_ws;
  unsigned short* xb = (unsigned short*)w;                       // 2 MB
  float* sq = (float*)(w + (size_t)NN * DD * 2);                 // 32 KB
  float* pscore = (float*)(w + (size_t)NN * DD * 2 + (size_t)NN * 4);  // 2.62 MB
  char* w3 = w + (size_t)NN * DD * 2 + (size_t)NN * 4 + (size_t)NN * 80 * 4;
  float* partial = (float*)w3;                                   // 256 B
  int* done = (int*)(w3 + NPART * 4);                            // 4 B

  prep_kernel<<<NN / 4, 256, 0, stream>>>(x, xb, sq, partial, done);
  dist_topk_kernel<<<dim3(NN / 256, CH), 256, 0, stream>>>(xb, sq, pscore);
  final_kernel<<<NN / 4, 256, 0, stream>>>(x, pos, pscore, partial, done, out);
}

// Round 13
// 106.415 us; speedup vs baseline: 1.2349x; 1.2349x over previous
//
#include <hip/hip_runtime.h>

#define NN 8192
#define DD 128
#define CH 16           // column chunks
#define CPC (NN / CH)   // cols per chunk = 512
#define TILES (CPC / 64)
#define NPART 64        // partial-sum bins

typedef __bf16 bf16x8 __attribute__((ext_vector_type(8)));
typedef float f32x4 __attribute__((ext_vector_type(4)));

#define PACK_INIT __uint_as_float(0x7F7FFFFFu)

// Pack (score, idx): high 19 bits of fp32 score, idx in low 13 (rounds 5-12,
// absmax 0.0 throughout).
static __device__ __forceinline__ float packsi(float s, unsigned idx) {
  return __uint_as_float((__float_as_uint(s) & 0xFFFFE000u) | idx);
}

// Sorted-insert via med3: closed form sk' = med3(v, s[k-1], sk), s0' = min.
// 5 ops (NET5) / 4 ops (NET4), dependency depth 1 — the round-11 win.
#define NET4(S0, S1, S2, S3, v)                                                \
  {                                                                            \
    float v_ = (v), o0 = S0, o1 = S1, o2 = S2;                                 \
    S0 = fminf(o0, v_);                                                        \
    S1 = __builtin_amdgcn_fmed3f(v_, o0, o1);                                  \
    S2 = __builtin_amdgcn_fmed3f(v_, o1, o2);                                  \
    S3 = __builtin_amdgcn_fmed3f(v_, o2, S3);                                  \
  }
#define NET5(S0, S1, S2, S3, S4, v)                                            \
  {                                                                            \
    float v_ = (v), o0 = S0, o1 = S1, o2 = S2, o3 = S3;                        \
    S0 = fminf(o0, v_);                                                        \
    S1 = __builtin_amdgcn_fmed3f(v_, o0, o1);                                  \
    S2 = __builtin_amdgcn_fmed3f(v_, o1, o2);                                  \
    S3 = __builtin_amdgcn_fmed3f(v_, o2, o3);                                  \
    S4 = __builtin_amdgcn_fmed3f(v_, o3, S4);                                  \
  }

static __device__ __forceinline__ unsigned short f2bf(float f) {
  unsigned u = __float_as_uint(f);
  u += 0x7FFFu + ((u >> 16) & 1u);   // round-to-nearest-even
  return (unsigned short)(u >> 16);
}

// Kernel 1: f32->bf16 convert, fp32 row sq-norms, zero partial bins.
__global__ __launch_bounds__(256) void prep_kernel(const float* __restrict__ x,
                                                   unsigned short* __restrict__ xb,
                                                   float* __restrict__ sq,
                                                   float* __restrict__ partial) {
  const int wave = threadIdx.x >> 6, lane = threadIdx.x & 63;
  const int row = blockIdx.x * 4 + wave;
  const float2 v = ((const float2*)(x + (size_t)row * DD))[lane];
  float ss = v.x * v.x + v.y * v.y;
#pragma unroll
  for (int off = 32; off; off >>= 1) ss += __shfl_down(ss, off);
  if (lane == 0) sq[row] = ss;
  unsigned packed = (unsigned)f2bf(v.x) | ((unsigned)f2bf(v.y) << 16);
  ((unsigned*)(xb + (size_t)row * DD))[lane] = packed;
  if (blockIdx.x == 0 && threadIdx.x < NPART) partial[threadIdx.x] = 0.0f;
}

// Kernel 2: LDS-staged bf16-MFMA scores + med3 packed top-k.
// 64 rows/wave (4 row-groups of 16 share every B fragment). Block = 256 rows
// x 512 cols; grid (32,16) = 512 blocks = 2/CU. Off-diagonal blocks keep
// top-4 (self absent); diagonal blocks (bx>>1==by) keep top-5.
// (Round-12 post-mortem: 4-buffer/half-barrier variant was neutral; the
// 2-buffer 1-barrier/tile form is kept as the simpler equal performer.)
__global__ __launch_bounds__(256, 2) void dist_topk_kernel(
    const unsigned short* __restrict__ xb, const float* __restrict__ sq,
    float* __restrict__ pscore) {
  const int t = threadIdx.x;
  const int wave = t >> 6, lane = t & 63;
  const int lrow = lane & 15, lquad = lane >> 4;
  const int rowBase = blockIdx.x * 256;
  const int chunk = blockIdx.y;
  const int j0 = chunk * CPC;
  const bool hasDiag = ((blockIdx.x >> 1) == (int)blockIdx.y);

  __shared__ unsigned short colsB[2][64 * DD];   // 2 x 16 KB, XOR-swizzled
  __shared__ float sqs[2][64];

  // A fragments for 4 row-groups: lane holds X[row][k=lquad*8+j].
  const int r0 = rowBase + wave * 64 + lrow;     // group g row = r0 + g*16
  const unsigned short* ap0 = xb + (size_t)(r0)*DD + lquad * 8;
  const unsigned short* ap1 = xb + (size_t)(r0 + 16) * DD + lquad * 8;
  const unsigned short* ap2 = xb + (size_t)(r0 + 32) * DD + lquad * 8;
  const unsigned short* ap3 = xb + (size_t)(r0 + 48) * DD + lquad * 8;
  bf16x8 a00 = *(const bf16x8*)(ap0), a01 = *(const bf16x8*)(ap0 + 32),
         a02 = *(const bf16x8*)(ap0 + 64), a03 = *(const bf16x8*)(ap0 + 96);
  bf16x8 a10 = *(const bf16x8*)(ap1), a11 = *(const bf16x8*)(ap1 + 32),
         a12 = *(const bf16x8*)(ap1 + 64), a13 = *(const bf16x8*)(ap1 + 96);
  bf16x8 a20 = *(const bf16x8*)(ap2), a21 = *(const bf16x8*)(ap2 + 32),
         a22 = *(const bf16x8*)(ap2 + 64), a23 = *(const bf16x8*)(ap2 + 96);
  bf16x8 a30 = *(const bf16x8*)(ap3), a31 = *(const bf16x8*)(ap3 + 32),
         a32 = *(const bf16x8*)(ap3 + 64), a33 = *(const bf16x8*)(ap3 + 96);

  // Packed sorted lists, one per row-group, named scalars.
  float q00 = PACK_INIT, q01 = PACK_INIT, q02 = PACK_INIT, q03 = PACK_INIT,
        q04 = PACK_INIT;
  float q10 = PACK_INIT, q11 = PACK_INIT, q12 = PACK_INIT, q13 = PACK_INIT,
        q14 = PACK_INIT;
  float q20 = PACK_INIT, q21 = PACK_INIT, q22 = PACK_INIT, q23 = PACK_INIT,
        q24 = PACK_INIT;
  float q30 = PACK_INIT, q31 = PACK_INIT, q32 = PACK_INIT, q33 = PACK_INIT,
        q34 = PACK_INIT;

  // Staging closed-form swizzle (round-5 verified).
  const int sr = t >> 4, sch = t & 15;
  const int dst0 = (sr << 4) | (sch ^ (sr & 15));

  const float4* srcv = (const float4*)(xb + (size_t)j0 * DD);
  float4 g0 = srcv[t], g1 = srcv[t + 256], g2 = srcv[t + 512], g3 = srcv[t + 768];
  float sqv = 0.0f;
  if (t < 64) sqv = sq[j0 + t];

#define KBODY(INSROW)                                                          \
  for (int it = 0; it < TILES; ++it) {                                         \
    const int jt = j0 + it * 64;                                               \
    const int cur = it & 1;                                                    \
    {                                                                          \
      float4* dstv = (float4*)colsB[cur];                                      \
      dstv[dst0] = g0;                                                         \
      dstv[dst0 + 256] = g1;                                                   \
      dstv[dst0 + 512] = g2;                                                   \
      dstv[dst0 + 768] = g3;                                                   \
      if (t < 64) sqs[cur][t] = sqv;                                           \
    }                                                                          \
    if (it + 1 < TILES) {                                                      \
      const float4* nsrc = (const float4*)(xb + (size_t)(jt + 64) * DD);       \
      g0 = nsrc[t]; g1 = nsrc[t + 256]; g2 = nsrc[t + 512]; g3 = nsrc[t + 768];\
      if (t < 64) sqv = sq[jt + 64 + t];                                       \
    }                                                                          \
    __syncthreads();                                                           \
    _Pragma("unroll")                                                          \
    for (int ct = 0; ct < 4; ++ct) {                                           \
      const unsigned short* bb = &colsB[cur][(ct * 16 + lrow) * DD];           \
      bf16x8 b0 = *(const bf16x8*)(bb + (((0 + lquad) ^ lrow) << 3));          \
      bf16x8 b1 = *(const bf16x8*)(bb + (((4 + lquad) ^ lrow) << 3));          \
      bf16x8 b2 = *(const bf16x8*)(bb + (((8 + lquad) ^ lrow) << 3));          \
      bf16x8 b3 = *(const bf16x8*)(bb + (((12 + lquad) ^ lrow) << 3));         \
      f32x4 ac0 = {0.f, 0.f, 0.f, 0.f}, ac1 = {0.f, 0.f, 0.f, 0.f};           \
      f32x4 ac2 = {0.f, 0.f, 0.f, 0.f}, ac3 = {0.f, 0.f, 0.f, 0.f};           \
      ac0 = __builtin_amdgcn_mfma_f32_16x16x32_bf16(b0, a00, ac0, 0, 0, 0);    \
      ac1 = __builtin_amdgcn_mfma_f32_16x16x32_bf16(b0, a10, ac1, 0, 0, 0);    \
      ac2 = __builtin_amdgcn_mfma_f32_16x16x32_bf16(b0, a20, ac2, 0, 0, 0);    \
      ac3 = __builtin_amdgcn_mfma_f32_16x16x32_bf16(b0, a30, ac3, 0, 0, 0);    \
      ac0 = __builtin_amdgcn_mfma_f32_16x16x32_bf16(b1, a01, ac0, 0, 0, 0);    \
      ac1 = __builtin_amdgcn_mfma_f32_16x16x32_bf16(b1, a11, ac1, 0, 0, 0);    \
      ac2 = __builtin_amdgcn_mfma_f32_16x16x32_bf16(b1, a21, ac2, 0, 0, 0);    \
      ac3 = __builtin_amdgcn_mfma_f32_16x16x32_bf16(b1, a31, ac3, 0, 0, 0);    \
      ac0 = __builtin_amdgcn_mfma_f32_16x16x32_bf16(b2, a02, ac0, 0, 0, 0);    \
      ac1 = __builtin_amdgcn_mfma_f32_16x16x32_bf16(b2, a12, ac1, 0, 0, 0);    \
      ac2 = __builtin_amdgcn_mfma_f32_16x16x32_bf16(b2, a22, ac2, 0, 0, 0);    \
      ac3 = __builtin_amdgcn_mfma_f32_16x16x32_bf16(b2, a32, ac3, 0, 0, 0);    \
      ac0 = __builtin_amdgcn_mfma_f32_16x16x32_bf16(b3, a03, ac0, 0, 0, 0);    \
      ac1 = __builtin_amdgcn_mfma_f32_16x16x32_bf16(b3, a13, ac1, 0, 0, 0);    \
      ac2 = __builtin_amdgcn_mfma_f32_16x16x32_bf16(b3, a23, ac2, 0, 0, 0);    \
      ac3 = __builtin_amdgcn_mfma_f32_16x16x32_bf16(b3, a33, ac3, 0, 0, 0);    \
      const f32x4 sq4 = *(const f32x4*)&sqs[cur][ct * 16 + lquad * 4];         \
      const unsigned colb = (unsigned)(jt + ct * 16 + lquad * 4);              \
      _Pragma("unroll")                                                        \
      for (int r = 0; r < 4; ++r) {                                            \
        INSROW(0, packsi(fmaf(-2.0f, ac0[r], sq4[r]), colb + r));              \
        INSROW(1, packsi(fmaf(-2.0f, ac1[r], sq4[r]), colb + r));              \
        INSROW(2, packsi(fmaf(-2.0f, ac2[r], sq4[r]), colb + r));              \
        INSROW(3, packsi(fmaf(-2.0f, ac3[r], sq4[r]), colb + r));              \
      }                                                                        \
    }                                                                          \
  }

#define INS4(G, V) NET4(q##G##0, q##G##1, q##G##2, q##G##3, (V))
#define INS5(G, V) NET5(q##G##0, q##G##1, q##G##2, q##G##3, q##G##4, (V))

  if (hasDiag) {
    KBODY(INS5)
  } else {
    KBODY(INS4)
  }
#undef KBODY

  // Merge across lquads (lanes sharing lrow hold the same 4 rows).
#define MERGE4(G, M)                                                           \
  {                                                                            \
    float o0 = __shfl_xor(q##G##0, M), o1 = __shfl_xor(q##G##1, M),            \
          o2 = __shfl_xor(q##G##2, M), o3 = __shfl_xor(q##G##3, M);            \
    NET4(q##G##0, q##G##1, q##G##2, q##G##3, o0);                              \
    NET4(q##G##0, q##G##1, q##G##2, q##G##3, o1);                              \
    NET4(q##G##0, q##G##1, q##G##2, q##G##3, o2);                              \
    NET4(q##G##0, q##G##1, q##G##2, q##G##3, o3);                              \
  }
#define MERGE5(G, M)                                                           \
  {                                                                            \
    float o0 = __shfl_xor(q##G##0, M), o1 = __shfl_xor(q##G##1, M),            \
          o2 = __shfl_xor(q##G##2, M), o3 = __shfl_xor(q##G##3, M),            \
          o4 = __shfl_xor(q##G##4, M);                                         \
    NET5(q##G##0, q##G##1, q##G##2, q##G##3, q##G##4, o0);                     \
    NET5(q##G##0, q##G##1, q##G##2, q##G##3, q##G##4, o1);                     \
    NET5(q##G##0, q##G##1, q##G##2, q##G##3, q##G##4, o2);                     \
    NET5(q##G##0, q##G##1, q##G##2, q##G##3, q##G##4, o3);                     \
    NET5(q##G##0, q##G##1, q##G##2, q##G##3, q##G##4, o4);                     \
  }
  if (hasDiag) {
    MERGE5(0, 16) MERGE5(1, 16) MERGE5(2, 16) MERGE5(3, 16)
    MERGE5(0, 32) MERGE5(1, 32) MERGE5(2, 32) MERGE5(3, 32)
  } else {
    MERGE4(0, 16) MERGE4(1, 16) MERGE4(2, 16) MERGE4(3, 16)
    MERGE4(0, 32) MERGE4(1, 32) MERGE4(2, 32) MERGE4(3, 32)
  }

  if (lquad == 0) {
    // pscore layout: [row][CH*5] -> coalesced per-row read in final_kernel.
    float* b0p = pscore + (size_t)(r0)*80 + chunk * 5;
    b0p[0] = q00; b0p[1] = q01; b0p[2] = q02; b0p[3] = q03; b0p[4] = q04;
    float* b1p = pscore + (size_t)(r0 + 16) * 80 + chunk * 5;
    b1p[0] = q10; b1p[1] = q11; b1p[2] = q12; b1p[3] = q13; b1p[4] = q14;
    float* b2p = pscore + (size_t)(r0 + 32) * 80 + chunk * 5;
    b2p[0] = q20; b2p[1] = q21; b2p[2] = q22; b2p[3] = q23; b2p[4] = q24;
    float* b3p = pscore + (size_t)(r0 + 48) * 80 + chunk * 5;
    b3p[0] = q30; b3p[1] = q31; b3p[2] = q32; b3p[3] = q33; b3p[4] = q34;
  }
}

// Kernel 3: chunk merge (packed) -> neg idx -> exact fp32 hinge -> 64 bins.
// (Round-12 lesson: do NOT fuse the bin fold via done-counter+threadfence —
// 2048 device-scope fences cost ~42 us. Separate tiny reduce is cheaper.)
__global__ __launch_bounds__(256) void final_kernel(const float* __restrict__ x,
                                                    const float* __restrict__ pos,
                                                    const float* __restrict__ pscore,
                                                    float* __restrict__ partial) {
  const int wave = threadIdx.x >> 6, lane = threadIdx.x & 63;
  const int row = blockIdx.x * 4 + wave;

  float q0 = PACK_INIT, q1 = PACK_INIT, q2 = PACK_INIT, q3 = PACK_INIT,
        q4 = PACK_INIT;
  if (lane < CH) {
    const float* b = pscore + (size_t)row * 80 + lane * 5;   // contiguous row
    q0 = b[0]; q1 = b[1]; q2 = b[2]; q3 = b[3]; q4 = b[4];
  }
#pragma unroll
  for (int m = 1; m < CH; m <<= 1) {
    float o0 = __shfl_xor(q0, m), o1 = __shfl_xor(q1, m), o2 = __shfl_xor(q2, m),
          o3 = __shfl_xor(q3, m), o4 = __shfl_xor(q4, m);
    NET5(q0, q1, q2, q3, q4, o0);
    NET5(q0, q1, q2, q3, q4, o1);
    NET5(q0, q1, q2, q3, q4, o2);
    NET5(q0, q1, q2, q3, q4, o3);
    NET5(q0, q1, q2, q3, q4, o4);
  }
  const int nidx = (int)(__float_as_uint(__shfl(q4, 0)) & 0x1FFFu);

  const float2 xv  = ((const float2*)(x   + (size_t)row  * DD))[lane];
  const float2 pv  = ((const float2*)(pos + (size_t)row  * DD))[lane];
  const float2 nvv = ((const float2*)(x   + (size_t)nidx * DD))[lane];
  float a0 = xv.x - pv.x + 1e-6f, a1 = xv.y - pv.y + 1e-6f;
  float b0 = xv.x - nvv.x + 1e-6f, b1 = xv.y - nvv.y + 1e-6f;
  float dap = a0 * a0 + a1 * a1;
  float dan = b0 * b0 + b1 * b1;
#pragma unroll
  for (int off = 32; off; off >>= 1) {
    dap += __shfl_down(dap, off);
    dan += __shfl_down(dan, off);
  }
  __shared__ float hs[4];
  if (lane == 0) hs[wave] = fmaxf(sqrtf(dap) - sqrtf(dan) + 0.3f, 0.0f);
  __syncthreads();
  if (threadIdx.x == 0) {
    float s = hs[0] + hs[1] + hs[2] + hs[3];
    atomicAdd(&partial[blockIdx.x & (NPART - 1)], s);
  }
}

// Kernel 4: one wave sums the 64 bins -> mean.
__global__ __launch_bounds__(64) void reduce_kernel(const float* __restrict__ partial,
                                                    float* __restrict__ out) {
  float v = partial[threadIdx.x];
#pragma unroll
  for (int off = 32; off; off >>= 1) v += __shfl_down(v, off);
  if (threadIdx.x == 0) out[0] = v * (1.0f / 8192.0f);
}

extern "C" void kernel_launch(void* const* d_in, const int* in_sizes, int n_in,
                              void* d_out, int out_size, void* d_ws, size_t ws_size,
                              hipStream_t stream) {
  const float* x   = (const float*)d_in[0];
  const float* pos = (const float*)d_in[1];
  float* out = (float*)d_out;

  char* w = (char*)d_ws;
  unsigned short* xb = (unsigned short*)w;                       // 2 MB
  float* sq = (float*)(w + (size_t)NN * DD * 2);                 // 32 KB
  float* pscore = (float*)(w + (size_t)NN * DD * 2 + (size_t)NN * 4);  // 2.62 MB
  float* partial = (float*)(w + (size_t)NN * DD * 2 + (size_t)NN * 4 +
                            (size_t)NN * 80 * 4);                // 256 B

  prep_kernel<<<NN / 4, 256, 0, stream>>>(x, xb, sq, partial);
  dist_topk_kernel<<<dim3(NN / 256, CH), 256, 0, stream>>>(xb, sq, pscore);
  final_kernel<<<NN / 4, 256, 0, stream>>>(x, pos, pscore, partial);
  reduce_kernel<<<1, 64, 0, stream>>>(partial, out);
}